// Round 6
// baseline (1081.618 us; speedup 1.0000x reference)
//
#include <hip/hip_runtime.h>
#include <cstdint>
#include <cstddef>

// Problem constants
static constexpr int Bn   = 4;
static constexpr int Sn   = 4096;
static constexpr int Hn   = 2048;
static constexpr int CINn = 4096;
static constexpr int COUTn= 4096;
static constexpr int GCn  = 512;    // CIN/G
static constexpr int Kt   = 4;      // conv taps
static constexpr int Mn   = Bn * Sn;   // 16384
static constexpr int SPn  = Sn + 3;    // padded rows per batch (3 zero rows in front)

typedef _Float16 half8 __attribute__((ext_vector_type(8)));
typedef _Float16 half4 __attribute__((ext_vector_type(4)));
typedef float    floatx4 __attribute__((ext_vector_type(4)));

// ---------------- prep kernels ----------------

__global__ void cvt_f32_f16(const float* __restrict__ src, _Float16* __restrict__ dst, int n4) {
    int i = blockIdx.x * blockDim.x + threadIdx.x;
    if (i < n4) {
        float4 v = ((const float4*)src)[i];
        half4 h;
        h[0] = (_Float16)v.x; h[1] = (_Float16)v.y;
        h[2] = (_Float16)v.z; h[3] = (_Float16)v.w;
        ((half4*)dst)[i] = h;
    }
}

// conv_w [COUT, 512, 4] fp32 -> Wc [COUT, k*512 + ci] fp16
__global__ void cvt_convw(const float* __restrict__ src, _Float16* __restrict__ dst) {
    int t = blockIdx.x * blockDim.x + threadIdx.x;   // 0 .. 4096*512
    int co = t >> 9, ci = t & 511;
    float4 v = ((const float4*)src)[(co << 9) + ci]; // src[co][ci][0..3] contiguous
    size_t base = (size_t)co * 2048 + ci;
    dst[base]        = (_Float16)v.x;
    dst[base + 512]  = (_Float16)v.y;
    dst[base + 1024] = (_Float16)v.z;
    dst[base + 1536] = (_Float16)v.w;
}

// zero the 3 leading pad rows of each batch in Hp [B*(S+3), 4096]
__global__ void zero_pads(_Float16* __restrict__ Hp) {
    int t = blockIdx.x * blockDim.x + threadIdx.x;   // 4 * 3*4096 = 49152
    int b = t / (3 * CINn);
    int off = t - b * (3 * CINn);
    Hp[(size_t)b * SPn * CINn + off] = (_Float16)0.f;
}

// ---------------- 256x256 / BK=64 / 8-wave GEMM, v5: m201 8-phase (fixed) ----
// C[m,n] = sum_k A[m,k]*B[n,k]  (B^T layout: K contiguous in both operands)
// MODE 0: stage1  A=Xh[16384,2048]            out: Hp fp16, padded rows, +b_in
// MODE 1: stage2  A=Hp (shifted conv gather)  out: Yh fp16, +conv_b, SiLU
// MODE 2: stage3  A=Yh[16384,4096]            out: fp32, +b_out
//
// v5 = v4 with the A-staging region fix. Read footprints (the v4 bug):
//   RD_A_H0 rows wm*128+0..63   -> A regions {0,2}  (wm=0: r0, wm=1: r2)
//   RD_A_H1 rows wm*128+64..127 -> A regions {1,3}
//   RD_B_Q0 rows wn*64+0..31, RD_B_Q1 rows wn*64+32..63 -> each touches the
//   lower/upper half of ALL FOUR B regions (region q = rows 64q..64q+63).
// So A-h0 stages MUST be regions {0,2}, A-h1 {1,3} (v4 staged {0,1}/{2,3} and
// clobbered region 1 before its ph3 readers -> absmax 4.7). B stages may go in
// any phase after the buffer's last B read phase (ph2 for buf0, ph6 for buf1).
//
// Iteration = 2 K-tiles (T even -> buf0, T+1 -> buf1: COMPILE-TIME buffer
// indices -> ds offsets fold to immediates). 8 phases/iter, each:
//   {ds_read subtile; stage half-tile; [lgkm(8) if 12 reads]; SB0; BAR;
//    lgkm(0); SB0; setprio(1); 16 MFMA (one C-quadrant); setprio(0);
//    [vmcnt(6) @ph4/ph8]; BAR}
// Stage slots (WAR: region's last reader phase strictly precedes the stage's
// preceding end-barrier; every phase drains lgkm to 0 before its end-barrier):
//   ph2: A{0,2}(T+2)   [last read ph1]     ph6: buf1 A{0,2}(T+3) [read ph5]
//   ph3: B{0,1}(T+2)   [all B reads done ph2]  ph7: buf1 B{0..3}(T+3) [done ph6]
//   ph4: A{1,3}(T+2)   [read ph3]          ph8: buf1 A{1,3}(T+3) [read ph7]
//   ph5: B{2,3}(T+2)   [done ph2]
// RAW induction (in-order vmcnt, 2 loads/thread/stage-slot, ph7=4):
// invariant: at iter entry outstanding = 6 = prev{ph7(4)+ph8(2)}.
// end-ph4 vmcnt(6): 6+6 -> retires prev ph7+ph8 = buf1 tile T+1's B(all)+A{1,3}
//   before ph5/ph7 read them (BAR follows).
// end-ph8 vmcnt(6): 6+10 -> retires ph2..ph6 = buf0 tile T+2 complete +
//   buf1 A{0,2}(T+3); keeps ph7+ph8 = 6. QED. Last iter: vmcnt(0), stages off.
// NT even for all stages (32/32/64).

__device__ __forceinline__ void async16(const void* g, void* l) {
    __builtin_amdgcn_global_load_lds(
        (__attribute__((address_space(1))) void*)(g),
        (__attribute__((address_space(3))) void*)(l),
        16, 0, 0);
}

#define BAR()  __builtin_amdgcn_s_barrier()
#define SB0()  __builtin_amdgcn_sched_barrier(0)
#define WL0()  asm volatile("s_waitcnt lgkmcnt(0)" ::: "memory")
#define WL8()  asm volatile("s_waitcnt lgkmcnt(8)" ::: "memory")
#define WV(n)  asm volatile("s_waitcnt vmcnt(" #n ")" ::: "memory")
#define PRIO1() __builtin_amdgcn_s_setprio(1)
#define PRIO0() __builtin_amdgcn_s_setprio(0)

template <int MODE>
__global__ __launch_bounds__(512, 2) void gemm8(
    const _Float16* __restrict__ A,
    const _Float16* __restrict__ Bw,
    const float* __restrict__ bias,
    void* __restrict__ outp,
    int Kd, int Ntiles)
{
    __shared__ __align__(16) _Float16 smem[2][2][256 * 64];   // [buf][A/B] 128 KiB

    const int t  = threadIdx.x;
    const int w  = t >> 6;        // wave 0..7
    const int l  = t & 63;
    const int wm = w >> 2;        // 2 wave rows
    const int wn = w & 3;         // 4 wave cols

    // bijective XCD swizzle (nwg % 8 == 0 for all stages)
    const int nwg = (int)gridDim.x;
    const int bid = (int)blockIdx.x;
    const int swz = (bid & 7) * (nwg >> 3) + (bid >> 3);
    const int mt = swz / Ntiles, nt = swz - mt * Ntiles;
    const int m0 = mt * 256, n0 = nt * 256;

    // --- staging addresses: thread t covers row (q*64 + t>>3), swizzled col block
    const int sr  = t >> 3;                        // 0..63
    const int scb = ((t & 7) ^ (sr & 7)) << 3;     // swizzled col, fp16 units
    const _Float16* pa[4];
    const _Float16* pb[4];
    #pragma unroll
    for (int q = 0; q < 4; ++q) {
        const int ma = m0 + q * 64 + sr;
        if (MODE == 1) {
            // A row for (m, tap k): b*(S+3) + s + k ; col: g*512 + ci
            pa[q] = A + ((size_t)((ma >> 12) * SPn + (ma & 4095)) << 12) + (n0 >> 9) * 512 + scb;
        } else {
            pa[q] = A + (size_t)ma * Kd + scb;
        }
        pb[q] = Bw + (size_t)(n0 + q * 64 + sr) * Kd + scb;
    }
    const int wst = w * 512;      // wave-uniform LDS offset within a region (fp16)

    const int fr = l & 15, quad = l >> 4, sw = fr & 7;

    floatx4 acc[8][4] = {};
    half8 afA[4][2];   // A-half0 of wave's 128 rows (rows wm*128 + mf*16 + fr)
    half8 afB[4][2];   // A-half1 (rows wm*128 + 64 + mf*16 + fr)
    half8 bf[4][2];    // bf[0..1]=B-q0 (rows wn*64+0..31), bf[2..3]=B-q1 (+32..63)

    const int NT = Kd >> 6;           // even for all stages
    const int NITER = NT >> 1;

#define KADJ(kk) ((MODE == 1) ? ((kk) + (((kk) >> 9) * 3584)) : (kk))
#define STA(b, q, ko) async16(pa[q] + (ko), &smem[b][0][(q) * 4096 + wst])
#define STB(b, q, ko) async16(pb[q] + (ko), &smem[b][1][(q) * 4096 + wst])

#define LCOL(ks) ((((ks << 2) + quad) ^ sw) << 3)

#define RD_A_H0(cb) do { \
    _Pragma("unroll") for (int mf = 0; mf < 4; ++mf) \
    _Pragma("unroll") for (int ks = 0; ks < 2; ++ks) { \
        int row = wm * 128 + mf * 16 + fr; \
        afA[mf][ks] = *(const half8*)(&smem[cb][0][row * 64 + LCOL(ks)]); \
    } } while (0)

#define RD_A_H1(cb) do { \
    _Pragma("unroll") for (int mf = 0; mf < 4; ++mf) \
    _Pragma("unroll") for (int ks = 0; ks < 2; ++ks) { \
        int row = wm * 128 + 64 + mf * 16 + fr; \
        afB[mf][ks] = *(const half8*)(&smem[cb][0][row * 64 + LCOL(ks)]); \
    } } while (0)

#define RD_B_Q0(cb) do { \
    _Pragma("unroll") for (int nf = 0; nf < 2; ++nf) \
    _Pragma("unroll") for (int ks = 0; ks < 2; ++ks) { \
        int row = wn * 64 + nf * 16 + fr; \
        bf[nf][ks] = *(const half8*)(&smem[cb][1][row * 64 + LCOL(ks)]); \
    } } while (0)

#define RD_B_Q1(cb) do { \
    _Pragma("unroll") for (int nf = 0; nf < 2; ++nf) \
    _Pragma("unroll") for (int ks = 0; ks < 2; ++ks) { \
        int row = wn * 64 + 32 + nf * 16 + fr; \
        bf[2 + nf][ks] = *(const half8*)(&smem[cb][1][row * 64 + LCOL(ks)]); \
    } } while (0)

// MMA_PH(AF, mh, nh): acc[mh*4+mf][nh*2+nf] += AF[mf][ks] * bf[nh*2+nf][ks]
#define MMA_PH(AF, mh, nh) do { \
    _Pragma("unroll") for (int mf = 0; mf < 4; ++mf) \
    _Pragma("unroll") for (int nf = 0; nf < 2; ++nf) \
    _Pragma("unroll") for (int ks = 0; ks < 2; ++ks) \
        acc[(mh) * 4 + mf][(nh) * 2 + nf] = __builtin_amdgcn_mfma_f32_16x16x32_f16( \
            AF[mf][ks], bf[(nh) * 2 + nf][ks], acc[(mh) * 4 + mf][(nh) * 2 + nf], 0, 0, 0); \
    } while (0)

    // --- prologue: tile0 -> buf0, tile1 -> buf1 (8 loads each); drain
    {
        STA(0, 0, 0); STA(0, 1, 0); STA(0, 2, 0); STA(0, 3, 0);
        STB(0, 0, 0); STB(0, 1, 0); STB(0, 2, 0); STB(0, 3, 0);
        const int ka1 = KADJ(64);
        STA(1, 0, ka1); STA(1, 1, ka1); STA(1, 2, ka1); STA(1, 3, ka1);
        STB(1, 0, 64); STB(1, 1, 64); STB(1, 2, 64); STB(1, 3, 64);
        WV(0); BAR();
    }

    for (int it = 0; it < NITER; ++it) {
        const int T = it << 1;
        const bool s2 = (T + 2 < NT);             // stage tile T+2 -> buf0
        const bool s3 = (T + 3 < NT);             // stage tile T+3 -> buf1
        const bool lastit = (it == NITER - 1);
        const int ka2 = KADJ((T + 2) << 6), kb2 = (T + 2) << 6;
        const int ka3 = KADJ((T + 3) << 6), kb3 = (T + 3) << 6;

        // ---- ph1: rd A-h0 + B-q0 (buf0); MMA(0,0) ----
        RD_A_H0(0); RD_B_Q0(0);
        WL8(); SB0(); BAR();
        WL0(); SB0();
        PRIO1(); MMA_PH(afA, 0, 0); PRIO0();
        BAR();

        // ---- ph2: rd B-q1 (buf0); stage A{0,2}(T+2); MMA(0,1) ----
        RD_B_Q1(0);
        if (s2) { STA(0, 0, ka2); STA(0, 2, ka2); }
        SB0(); BAR();
        WL0(); SB0();
        PRIO1(); MMA_PH(afA, 0, 1); PRIO0();
        BAR();

        // ---- ph3: rd A-h1 (buf0); stage B{0,1}(T+2); MMA(1,0) ----
        RD_A_H1(0);
        if (s2) { STB(0, 0, kb2); STB(0, 1, kb2); }
        SB0(); BAR();
        WL0(); SB0();
        PRIO1(); MMA_PH(afB, 1, 0); PRIO0();
        BAR();

        // ---- ph4: stage A{1,3}(T+2); MMA(1,1); vmcnt ----
        if (s2) { STA(0, 1, ka2); STA(0, 3, ka2); }
        SB0(); BAR();
        PRIO1(); MMA_PH(afB, 1, 1); PRIO0();
        if (lastit) { WV(0); } else { WV(6); }
        BAR();

        // ---- ph5: rd A-h0 + B-q0 (buf1); stage B{2,3}(T+2); MMA(0,0) ----
        RD_A_H0(1); RD_B_Q0(1);
        if (s2) { STB(0, 2, kb2); STB(0, 3, kb2); }
        WL8(); SB0(); BAR();
        WL0(); SB0();
        PRIO1(); MMA_PH(afA, 0, 0); PRIO0();
        BAR();

        // ---- ph6: rd B-q1 (buf1); stage buf1 A{0,2}(T+3); MMA(0,1) ----
        RD_B_Q1(1);
        if (s3) { STA(1, 0, ka3); STA(1, 2, ka3); }
        SB0(); BAR();
        WL0(); SB0();
        PRIO1(); MMA_PH(afA, 0, 1); PRIO0();
        BAR();

        // ---- ph7: rd A-h1 (buf1); stage buf1 B{0..3}(T+3); MMA(1,0) ----
        RD_A_H1(1);
        if (s3) { STB(1, 0, kb3); STB(1, 1, kb3); STB(1, 2, kb3); STB(1, 3, kb3); }
        SB0(); BAR();
        WL0(); SB0();
        PRIO1(); MMA_PH(afB, 1, 0); PRIO0();
        BAR();

        // ---- ph8: stage buf1 A{1,3}(T+3); MMA(1,1); vmcnt ----
        if (s3) { STA(1, 1, ka3); STA(1, 3, ka3); }
        SB0(); BAR();
        PRIO1(); MMA_PH(afB, 1, 1); PRIO0();
        if (lastit) { WV(0); } else { WV(6); }
        BAR();
    }

    // --- epilogue: D[row=(l>>4)*4+r][col=l&15] per 16x16 subtile ---
    #pragma unroll
    for (int nf = 0; nf < 4; ++nf) {
        const int ncol = n0 + wn * 64 + nf * 16 + fr;
        const float bv = bias[ncol];
        #pragma unroll
        for (int mf = 0; mf < 8; ++mf) {
            const int mb = m0 + wm * 128 + mf * 16 + quad * 4;
            #pragma unroll
            for (int r = 0; r < 4; ++r) {
                const int m = mb + r;
                float v = acc[mf][nf][r] + bv;
                if (MODE == 0) {
                    const size_t row = (size_t)((m >> 12) * SPn + 3 + (m & 4095));
                    ((_Float16*)outp)[(row << 12) + ncol] = (_Float16)v;
                } else if (MODE == 1) {
                    v = v * (1.0f / (1.0f + __expf(-v)));   // SiLU
                    ((_Float16*)outp)[((size_t)m << 12) + ncol] = (_Float16)v;
                } else {
                    ((float*)outp)[((size_t)m << 11) + ncol] = v;
                }
            }
        }
    }
#undef KADJ
#undef STA
#undef STB
#undef LCOL
#undef RD_A_H0
#undef RD_A_H1
#undef RD_B_Q0
#undef RD_B_Q1
#undef MMA_PH
}

// ---------------- launch ----------------

extern "C" void kernel_launch(void* const* d_in, const int* in_sizes, int n_in,
                              void* d_out, int out_size, void* d_ws, size_t ws_size,
                              hipStream_t stream) {
    const float* x      = (const float*)d_in[0];
    const float* W_in   = (const float*)d_in[1];
    const float* b_in   = (const float*)d_in[2];
    const float* conv_w = (const float*)d_in[3];
    const float* conv_b = (const float*)d_in[4];
    const float* W_out  = (const float*)d_in[5];
    const float* b_out  = (const float*)d_in[6];
    float* out = (float*)d_out;

    // workspace layout (bytes) — total ~368 MB
    char* ws = (char*)d_ws;
    _Float16* Xh  = (_Float16*)(ws);                         //  67,108,864  x fp16 [16384,2048]
    _Float16* W1h = (_Float16*)(ws + 67108864);              //  16,777,216  W_in fp16 [4096,2048]
    _Float16* Wch = (_Float16*)(ws + 83886080);              //  16,777,216  conv_w fp16 [4096,2048]
    _Float16* W2h = (_Float16*)(ws + 100663296);             //  16,777,216  W_out fp16 [2048,4096]
    _Float16* Hp  = (_Float16*)(ws + 117440512);             // 134,316,032  h fp16 [4*(4096+3),4096]
    _Float16* Yh  = (_Float16*)(ws + 251756544);             // 134,217,728  y fp16 [16384,4096]
    (void)ws_size; (void)in_sizes; (void)n_in; (void)out_size;

    cvt_f32_f16<<<32768, 256, 0, stream>>>(x,     Xh,  Mn * Hn / 4);
    cvt_f32_f16<<<8192,  256, 0, stream>>>(W_in,  W1h, CINn * Hn / 4);
    cvt_convw <<<8192,  256, 0, stream>>>(conv_w, Wch);
    cvt_f32_f16<<<8192,  256, 0, stream>>>(W_out, W2h, Hn * COUTn / 4);
    zero_pads <<<192,   256, 0, stream>>>(Hp);

    // stage 1: h = x @ W_in^T + b_in        -> Hp (padded, fp16)
    gemm8<0><<<(Mn / 256) * (CINn / 256), 512, 0, stream>>>(Xh, W1h, b_in, (void*)Hp, Hn, CINn / 256);
    // stage 2: y = silu(causal_gconv(h) + conv_b) -> Yh (fp16)
    gemm8<1><<<(Mn / 256) * (COUTn / 256), 512, 0, stream>>>(Hp, Wch, conv_b, (void*)Yh, GCn * Kt, COUTn / 256);
    // stage 3: out = y @ W_out^T + b_out    -> fp32
    gemm8<2><<<(Mn / 256) * (Hn / 256), 512, 0, stream>>>(Yh, W2h, b_out, (void*)out, COUTn, Hn / 256);
}